// Round 9
// baseline (118.221 us; speedup 1.0000x reference)
//
#include <hip/hip_runtime.h>
#include <cstdint>

#define DD   256   // embedding dim
#define NS   320   // n_support
#define NQ   2048  // n_query
#define NWAY 20
#define QTP  8     // query rows per block (256 x 8 = 2048)
#define NSP  2     // support rows per block (blocks 0..159)
#define SBLK 160
#define NBLK 256   // grid == CU count; +dyn LDS forces 1 block/CU (co-resident)
#define CMAX 64    // max supports per class
#define MAGICF 0x1357BEEF0DDC0FFEULL  // halves differ -> never equals poison fill

typedef _Float16 f16x2 __attribute__((ext_vector_type(2)));

__device__ __forceinline__ f16x2 u2f(unsigned u) {
  f16x2 f; __builtin_memcpy(&f, &u, 4); return f;
}

// acc += dot(relu(q + s), w) over a d-pair: 3 VALU per 2 elements, f32 accum.
__device__ __forceinline__ float relu_dot2(f16x2 q, f16x2 s, f16x2 w, float c) {
  f16x2 h = q + s;
  const f16x2 z = {(_Float16)0.f, (_Float16)0.f};
  h = __builtin_elementwise_max(h, z);
#if __has_builtin(__builtin_amdgcn_fdot2)
  return __builtin_amdgcn_fdot2(h, w, c, false);
#else
  return c + (float)h.x * (float)w.x + (float)h.y * (float)w.y;
#endif
}

// Fused proj + matchnet. Phase 1 = R8 proj body (HARD-WON: rows<=10, single
// readfirstlane base + imm offsets, unroll 8). q-projections stay in LDS
// (phase 2 of block b consumes exactly block b's 8 rows); W2 converted
// per-block; spb2 is the ONLY cross-block buffer, protected by a device-scope
// spin barrier (all 256 blocks co-resident: grid==CU count, 1 block/CU via
// 90 KB total LDS). Phase 2 = R4 matchnet (QT=8 @ 256 blocks, measured
// neutral vs QT=4 @ 512), q/W2 via uniform ds_read_b128 broadcast.
__global__ __launch_bounds__(1024, 4) void fused_kernel(
    const float* __restrict__ sup, const float* __restrict__ qe,
    const float* __restrict__ W1, const float* __restrict__ b1,
    const float* __restrict__ W2, const int* __restrict__ labels,
    f16x2* __restrict__ spb2, unsigned long long* __restrict__ flag,
    unsigned int* __restrict__ cnt, float* __restrict__ out) {
  __shared__ float pacc[3][QTP + NSP][DD];   // 30 KB k-combine
  __shared__ _Float16 qlds[QTP][DD];         // 4 KB: this block's q rows (f16)
  __shared__ _Float16 w2l[DD];               // 512 B: local W2 f16
  __shared__ float wexp[QTP][NS];            // 10 KB
  __shared__ float wm[5];
  __shared__ float csum[QTP * NWAY];
  __shared__ int   ccnt[NWAY];
  __shared__ short cidx[NWAY * CMAX];
  extern __shared__ char occupancy_pad[];    // +41 KB dyn -> >80 KB -> 1 blk/CU

  const int t = threadIdx.x;
  const int b = blockIdx.x;

  if (b == 0 && t == 0) {   // init barrier state; others gated on magic flag
    __hip_atomic_store(cnt, 0u, __ATOMIC_RELAXED, __HIP_MEMORY_SCOPE_AGENT);
    __threadfence();
    __hip_atomic_store(flag, (unsigned long long)MAGICF, __ATOMIC_RELEASE,
                       __HIP_MEMORY_SCOPE_AGENT);
  }

  // ---------------- phase 1: projections (R8 body) ----------------
  const int d  = t & 255;
  const int kq = t >> 8;               // 0..3, wave-uniform
  const int r0 = b * QTP;
  const bool hasS = (b < SBLK);
  const int s0 = hasS ? b * NSP : 0;

  const float* wq = W1 + (size_t)(kq * 64) * DD + d;   // query quarter
  const float* wsup = wq + (size_t)DD * DD;            // support quarter
  const float* qbase = qe  + __builtin_amdgcn_readfirstlane(r0 * DD + kq * 64);
  const float* sbase = sup + __builtin_amdgcn_readfirstlane(s0 * DD + kq * 64);

  if (kq == 0) w2l[d] = (_Float16)W2[d];   // per-block W2 -> f16

  float acc[QTP] = {};
  float accs[NSP] = {};
  if (hasS) {
#pragma unroll 8
    for (int k = 0; k < 64; ++k) {
      const float wv = wq[(size_t)k * DD];       // coalesced, L2-resident
#pragma unroll
      for (int i = 0; i < QTP; ++i)
        acc[i] += qbase[i * DD + k] * wv;        // uniform base + imm -> s_load
      const float wvs = wsup[(size_t)k * DD];
      accs[0] += sbase[k] * wvs;
      accs[1] += sbase[DD + k] * wvs;
    }
  } else {
#pragma unroll 8
    for (int k = 0; k < 64; ++k) {
      const float wv = wq[(size_t)k * DD];
#pragma unroll
      for (int i = 0; i < QTP; ++i)
        acc[i] += qbase[i * DD + k] * wv;
    }
  }
  if (kq) {
#pragma unroll
    for (int i = 0; i < QTP; ++i) pacc[kq - 1][i][d] = acc[i];
    if (hasS) {
#pragma unroll
      for (int j = 0; j < NSP; ++j) pacc[kq - 1][QTP + j][d] = accs[j];
    }
  }
  __syncthreads();
  if (kq == 0) {
#pragma unroll
    for (int i = 0; i < QTP; ++i) {
      const float v = acc[i] + pacc[0][i][d] + pacc[1][i][d] + pacc[2][i][d];
      qlds[i][d] = (_Float16)v;          // same f16 cast as qph path
    }
    if (hasS) {
      const float bb = b1[d];
#pragma unroll
      for (int j = 0; j < NSP; ++j) {
        const float v = accs[j] + pacc[0][QTP + j][d] + pacc[1][QTP + j][d] +
                        pacc[2][QTP + j][d] + bb;
        const float vh = __shfl_down(v, 1);      // lane 2k gets d=2k+1's value
        if (!(d & 1)) {
          f16x2 p = {(_Float16)v, (_Float16)vh};
          spb2[(size_t)(d >> 1) * NS + (s0 + j)] = p;
        }
      }
    }
  }

  // ---------------- grid barrier (spb2 is the only cross-block data) -------
  if (t < NWAY) ccnt[t] = 0;
  __syncthreads();                       // all waves' spb2 stores drained
  if (t == 0) {
    __threadfence();                     // publish spb2 device-wide
    int g = 0;
    while (__hip_atomic_load(flag, __ATOMIC_ACQUIRE,
                             __HIP_MEMORY_SCOPE_AGENT) != MAGICF &&
           ++g < (1 << 24)) __builtin_amdgcn_s_sleep(2);
    atomicAdd(cnt, 1u);
    g = 0;
    while (__hip_atomic_load(cnt, __ATOMIC_RELAXED,
                             __HIP_MEMORY_SCOPE_AGENT) < NBLK &&
           ++g < (1 << 24)) __builtin_amdgcn_s_sleep(2);
    __threadfence();                     // acquire: drop stale cached lines
  }
  __syncthreads();

  // ---------------- phase 2: matchnet (R4 body, QT=8, q/W2 from LDS) ------
  const int half = t / NS;               // 0,1 compute; >=2 idle waves
  const int s    = t - half * NS;
  if (half == 0) {                       // per-class index lists
    const int lab  = labels[s];
    const int slot = atomicAdd(&ccnt[lab], 1);
    cidx[lab * CMAX + slot] = (short)s;
  }

  float acc2[QTP] = {};
  if (half < 2) {
    const int d0 = half * (DD / 2);
    const f16x2* sb = spb2 + (size_t)(d0 >> 1) * NS + s;
#pragma unroll 2
    for (int dd = 0; dd < DD / 2; dd += 8) {     // 8 d's = 4 pairs per step
      const int dp = dd >> 1;
      const f16x2 sv0 = sb[(dp + 0) * NS];       // coalesced b32, L2/L3
      const f16x2 sv1 = sb[(dp + 1) * NS];
      const f16x2 sv2 = sb[(dp + 2) * NS];
      const f16x2 sv3 = sb[(dp + 3) * NS];
      const uint4 wv = *reinterpret_cast<const uint4*>(&w2l[d0 + dd]);  // ds bcast
      const f16x2 w0 = u2f(wv.x), w1 = u2f(wv.y), w2v = u2f(wv.z), w3 = u2f(wv.w);
#pragma unroll
      for (int i = 0; i < QTP; ++i) {
        const uint4 qv = *reinterpret_cast<const uint4*>(&qlds[i][d0 + dd]);
        float a = acc2[i];
        a = relu_dot2(u2f(qv.x), sv0, w0, a);
        a = relu_dot2(u2f(qv.y), sv1, w1, a);
        a = relu_dot2(u2f(qv.z), sv2, w2v, a);
        a = relu_dot2(u2f(qv.w), sv3, w3, a);
        acc2[i] = a;
      }
    }
  }

  if (half == 1) {
#pragma unroll
    for (int i = 0; i < QTP; ++i) wexp[i][s] = acc2[i];
  }
  __syncthreads();
  float m = -1e30f;
  if (half == 0) {
#pragma unroll
    for (int i = 0; i < QTP; ++i) { acc2[i] += wexp[i][s]; m = fmaxf(m, acc2[i]); }
#pragma unroll
    for (int off = 32; off > 0; off >>= 1)
      m = fmaxf(m, __shfl_xor(m, off));
    if ((t & 63) == 0) wm[t >> 6] = m;
  }
  __syncthreads();
  if (half == 0) {
    const float M = fmaxf(fmaxf(fmaxf(wm[0], wm[1]), fmaxf(wm[2], wm[3])), wm[4]);
#pragma unroll
    for (int i = 0; i < QTP; ++i) wexp[i][s] = __expf(acc2[i] - M);
  }
  __syncthreads();
  if (t < QTP * NWAY) {                  // per-(query,class) sums
    const int i = t / NWAY, c = t - i * NWAY;
    const int n = ccnt[c];
    float sum = 0.f;
    for (int j = 0; j < n; ++j) sum += wexp[i][cidx[c * CMAX + j]];
    csum[t] = sum;
  }
  __syncthreads();
  if (t < QTP * NWAY) {
    const int i = t / NWAY, c = t - i * NWAY;
    float tot = 0.f;
#pragma unroll
    for (int j = 0; j < NWAY; ++j) tot += csum[i * NWAY + j];
    out[(size_t)(b * QTP + i) * NWAY + c] = csum[t] / tot;
  }
}

extern "C" void kernel_launch(void* const* d_in, const int* in_sizes, int n_in,
                              void* d_out, int out_size, void* d_ws, size_t ws_size,
                              hipStream_t stream) {
  const float* sup = (const float*)d_in[0];   // [320,256]
  const float* qe  = (const float*)d_in[1];   // [2048,256]
  const int*   lab = (const int*)d_in[2];     // [320] int32
  const float* W1  = (const float*)d_in[3];   // [512,256]
  const float* b1  = (const float*)d_in[4];   // [256]
  const float* W2  = (const float*)d_in[5];   // [256]
  // b2 (d_in[6]) softmax-invariant -> unused. n_way/n_shot hardcoded.
  float* out = (float*)d_out;                 // [2048,20]
  char* wsp = (char*)d_ws;
  f16x2* spb2 = (f16x2*)wsp;                                   // 160 KB
  unsigned long long* flag = (unsigned long long*)(wsp + 256 * 1024);
  unsigned int* cnt = (unsigned int*)(wsp + 256 * 1024 + 8);

  fused_kernel<<<NBLK, 1024, 41 * 1024, stream>>>(sup, qe, W1, b1, W2, lab,
                                                  spb2, flag, cnt, out);
}

// Round 10
// 90.912 us; speedup vs baseline: 1.3004x; 1.3004x over previous
//
#include <hip/hip_runtime.h>
#include <cstdint>

#define DD   256   // embedding dim
#define NS   320   // n_support
#define NQ   2048  // n_query
#define NWAY 20
#define QTP  8     // query rows per proj block (256 blocks x 8 = 2048)
#define NSP  2     // support rows per mixed proj block
#define SBLK 160   // blocks 0..159 carry 2 support rows each (320 total)
#define QT   4     // queries per matchnet block (QT=8 measured neutral; keep 4)
#define CMAX 64    // max supports per class (labels random, ~16 each)

typedef _Float16 f16x2 __attribute__((ext_vector_type(2)));

__device__ __forceinline__ f16x2 u2f(unsigned u) {
  f16x2 f; __builtin_memcpy(&f, &u, 4); return f;
}

// acc += dot(relu(q + s), w) over a d-pair: v_pk_add_f16 + v_pk_max_f16 +
// v_dot2_f32_f16 = 3 VALU per 2 elements (vs 6 in f32). f32 accumulate.
__device__ __forceinline__ float relu_dot2(f16x2 q, f16x2 s, f16x2 w, float c) {
  f16x2 h = q + s;
  const f16x2 z = {(_Float16)0.f, (_Float16)0.f};
  h = __builtin_elementwise_max(h, z);
#if __has_builtin(__builtin_amdgcn_fdot2)
  return __builtin_amdgcn_fdot2(h, w, c, false);
#else
  return c + (float)h.x * (float)w.x + (float)h.y * (float)w.y;
#endif
}

// Fused projections, k-split-4 across 1024 threads (d = t&255, kq = t>>8).
// 256 uniform blocks (1/CU). Blocks 0..159: 8 query rows + 2 support rows;
// blocks 160..255: 8 query rows only — they skip the support half of W1,
// cutting W1 L2 traffic 134 -> 108 MB (R8: -0.5 us, confirmed L2-bound).
// HARD-WON CONSTRAINTS (R4/R5/R7 each cost +4 us; R9 fusion cost +27 us):
//   - rows/block <= 10 (SGPR cliff: rows x unroll8 scalar loads must fit)
//   - single wave-uniform readfirstlane base + compile-time imm offsets
//   - #pragma unroll 8
//   - two kernels, NOT a fused grid-barrier kernel (agent-scope spin across
//     8 non-coherent XCD L2s measured ~50 us — launch gap is far cheaper)
// f32 accumulate; epilogue emits the f16 matchnet operands:
//   qph  [q][d]   f16 row-major (consumed via s_load_dwordx4 -> 4 d-pairs)
//   spb2 [d/2][s] f16x2 d-pair-major (consumed as coalesced b32 per lane)
//   w2h  [d]      f16 (block 0 converts W2 once)
__global__ __launch_bounds__(1024) void proj_kernel(
    const float* __restrict__ sup, const float* __restrict__ qe,
    const float* __restrict__ W1, const float* __restrict__ b1,
    const float* __restrict__ W2,
    _Float16* __restrict__ qph, f16x2* __restrict__ spb2,
    _Float16* __restrict__ w2h) {
  __shared__ float pacc[3][QTP + NSP][DD];   // 30 KB k-combine buffer
  const int t  = threadIdx.x;
  const int d  = t & 255;
  const int kq = t >> 8;               // 0..3, wave-uniform
  const int b  = blockIdx.x;
  const int r0 = b * QTP;              // query rows, always all valid
  const bool hasS = (b < SBLK);
  const int s0 = hasS ? b * NSP : 0;

  const float* wq = W1 + (size_t)(kq * 64) * DD + d;          // query quarter
  const float* ws = wq + (size_t)DD * DD;                     // support quarter
  const float* qbase = qe  + __builtin_amdgcn_readfirstlane(r0 * DD + kq * 64);
  const float* sbase = sup + __builtin_amdgcn_readfirstlane(s0 * DD + kq * 64);

  if (b == 0 && kq == 0) w2h[d] = (_Float16)W2[d];   // one-time W2 -> f16

  float acc[QTP] = {};
  float accs[NSP] = {};
  if (hasS) {
#pragma unroll 8
    for (int k = 0; k < 64; ++k) {
      const float wv = wq[(size_t)k * DD];       // coalesced, L2-resident
#pragma unroll
      for (int i = 0; i < QTP; ++i)
        acc[i] += qbase[i * DD + k] * wv;        // uniform base + imm -> s_load
      const float wvs = ws[(size_t)k * DD];
      accs[0] += sbase[k] * wvs;
      accs[1] += sbase[DD + k] * wvs;
    }
  } else {
#pragma unroll 8
    for (int k = 0; k < 64; ++k) {
      const float wv = wq[(size_t)k * DD];
#pragma unroll
      for (int i = 0; i < QTP; ++i)
        acc[i] += qbase[i * DD + k] * wv;
    }
  }
  if (kq) {
#pragma unroll
    for (int i = 0; i < QTP; ++i) pacc[kq - 1][i][d] = acc[i];
    if (hasS) {
#pragma unroll
      for (int j = 0; j < NSP; ++j) pacc[kq - 1][QTP + j][d] = accs[j];
    }
  }
  __syncthreads();
  if (kq == 0) {
#pragma unroll
    for (int i = 0; i < QTP; ++i) {
      const float v = acc[i] + pacc[0][i][d] + pacc[1][i][d] + pacc[2][i][d];
      qph[(size_t)(r0 + i) * DD + d] = (_Float16)v;   // coalesced b16
    }
    if (hasS) {
      const float bb = b1[d];
#pragma unroll
      for (int j = 0; j < NSP; ++j) {
        const float v = accs[j] + pacc[0][QTP + j][d] + pacc[1][QTP + j][d] +
                        pacc[2][QTP + j][d] + bb;
        const float vh = __shfl_down(v, 1);      // lane 2k gets d=2k+1's value
        if (!(d & 1)) {
          f16x2 p = {(_Float16)v, (_Float16)vh}; // .x = even d, .y = odd d
          spb2[(size_t)(d >> 1) * NS + (s0 + j)] = p;
        }
      }
    }
  }
}

// matchnet: 512 blocks x 640 threads (10 waves, 2 blocks/CU -> 5 waves/SIMD).
// Waves 0-4: s=t, d in [0,128); waves 5-9: same supports, d in [128,256).
// f16 packed datapath: per 8 d's per query = 4x{pk_add, pk_max, dot2} = 12 VALU
// (halved vs f32). sv coalesced b32 (VMEM, L2); q/W2 wave-uniform -> s_load.
// Measured: VALU/latency-bound (sv traffic halving via QT=8 was neutral).
// Epilogue (f32): combine halves, block softmax, per-class sums via label
// index lists (classes NOT balanced).
__global__ __launch_bounds__(640) void matchnet_kernel(
    const _Float16* __restrict__ qph, const f16x2* __restrict__ spb2,
    const _Float16* __restrict__ w2h, const int* __restrict__ labels,
    float* __restrict__ out) {
  __shared__ float wexp[QT][NS];        // d-half partials, then exp weights
  __shared__ float wm[5];
  __shared__ float csum[QT * NWAY];
  __shared__ int   ccnt[NWAY];
  __shared__ short cidx[NWAY * CMAX];
  const int t    = threadIdx.x;
  const int q0   = blockIdx.x * QT;
  const int half = t / NS;              // wave-uniform (NS = 5 waves)
  const int s    = t - half * NS;

  if (t < NWAY) ccnt[t] = 0;
  __syncthreads();
  if (!half) {                          // build per-class index lists
    const int lab  = labels[s];
    const int slot = atomicAdd(&ccnt[lab], 1);
    cidx[lab * CMAX + slot] = (short)s;
  }

  const int d0 = half * (DD / 2);
  const _Float16* qb = qph + __builtin_amdgcn_readfirstlane(q0 * DD + d0);
  const _Float16* wb = w2h + d0;
  const f16x2*    sb = spb2 + (size_t)(d0 >> 1) * NS + s;

  float acc[QT] = {};
#pragma unroll 2
  for (int dd = 0; dd < DD / 2; dd += 8) {       // 8 d's = 4 pairs per step
    const int dp = dd >> 1;
    const f16x2 sv0 = sb[(dp + 0) * NS];         // coalesced b32, L1/L2
    const f16x2 sv1 = sb[(dp + 1) * NS];
    const f16x2 sv2 = sb[(dp + 2) * NS];
    const f16x2 sv3 = sb[(dp + 3) * NS];
    const uint4 wv = *reinterpret_cast<const uint4*>(wb + dd);  // s_load_dwordx4
    const f16x2 w0 = u2f(wv.x), w1 = u2f(wv.y), w2 = u2f(wv.z), w3 = u2f(wv.w);
#pragma unroll
    for (int i = 0; i < QT; ++i) {
      const uint4 qv = *reinterpret_cast<const uint4*>(qb + i * DD + dd);  // s_load
      float a = acc[i];
      a = relu_dot2(u2f(qv.x), sv0, w0, a);
      a = relu_dot2(u2f(qv.y), sv1, w1, a);
      a = relu_dot2(u2f(qv.z), sv2, w2, a);
      a = relu_dot2(u2f(qv.w), sv3, w3, a);
      acc[i] = a;
    }
  }

  // Combine d-halves.
  if (half) {
#pragma unroll
    for (int i = 0; i < QT; ++i) wexp[i][s] = acc[i];
  }
  __syncthreads();
  float m = -1e30f;
  if (!half) {
#pragma unroll
    for (int i = 0; i < QT; ++i) { acc[i] += wexp[i][s]; m = fmaxf(m, acc[i]); }
#pragma unroll
    for (int off = 32; off > 0; off >>= 1)
      m = fmaxf(m, __shfl_xor(m, off));
    if ((t & 63) == 0) wm[t >> 6] = m;
  }
  __syncthreads();
  if (!half) {
    const float M = fmaxf(fmaxf(fmaxf(wm[0], wm[1]), fmaxf(wm[2], wm[3])), wm[4]);
#pragma unroll
    for (int i = 0; i < QT; ++i) wexp[i][s] = __expf(acc[i] - M);
  }
  __syncthreads();
  // Per-(query,class) sums over that class's supports (variable count).
  if (t < QT * NWAY) {
    const int i = t / NWAY, c = t - i * NWAY;
    const int n = ccnt[c];
    float sum = 0.f;
    for (int j = 0; j < n; ++j) sum += wexp[i][cidx[c * CMAX + j]];
    csum[t] = sum;
  }
  __syncthreads();
  if (t < QT * NWAY) {
    const int i = t / NWAY, c = t - i * NWAY;
    float tot = 0.f;
#pragma unroll
    for (int j = 0; j < NWAY; ++j) tot += csum[i * NWAY + j];
    out[(size_t)(q0 + i) * NWAY + c] = csum[t] / tot;
  }
}

extern "C" void kernel_launch(void* const* d_in, const int* in_sizes, int n_in,
                              void* d_out, int out_size, void* d_ws, size_t ws_size,
                              hipStream_t stream) {
  const float* sup = (const float*)d_in[0];   // [320,256]
  const float* qe  = (const float*)d_in[1];   // [2048,256]
  const int*   lab = (const int*)d_in[2];     // [320] int32
  const float* W1  = (const float*)d_in[3];   // [512,256]
  const float* b1  = (const float*)d_in[4];   // [256]
  const float* W2  = (const float*)d_in[5];   // [256]
  // b2 (d_in[6]) softmax-invariant -> unused. n_way/n_shot hardcoded.
  float* out = (float*)d_out;                 // [2048,20]
  char* ws = (char*)d_ws;
  f16x2*    spb2 = (f16x2*)ws;                         // 128*320*4B = 160 KB
  _Float16* qph  = (_Float16*)(ws + 256 * 1024);       // 2048*256*2B = 1 MB
  _Float16* w2h  = (_Float16*)(ws + 256 * 1024 + 1024 * 1024);  // 512 B

  proj_kernel<<<NQ / QTP, 1024, 0, stream>>>(sup, qe, W1, b1, W2, qph, spb2, w2h);
  matchnet_kernel<<<NQ / QT, 640, 0, stream>>>(qph, spb2, w2h, lab, out);
}